// Round 8
// baseline (239.263 us; speedup 1.0000x reference)
//
#include <hip/hip_runtime.h>

#define IMG_H 512
#define IMG_W 512
#define NCLS  21
#define HWC   (IMG_H * IMG_W)   // 262144 = 2^18

// 1/ln(501)
#define INV_LOG_MAXR 0.16085936f

// ---------------- union-find ----------------
// Lock-free union-find, union-by-min + path halving (ECL-CC style).
// Plain loads are safe: any published parent value is a true ancestor
// (parents only decrease), CAS return values drive progress in unite(),
// and kernel boundaries make all CAS results visible to plain loads.

__device__ __forceinline__ int find_root(int* parent, int x) {
    int p = parent[x];
    while (p != x) {
        int gp = parent[p];
        if (gp != p) parent[x] = gp;   // path halving: gp is an ancestor
        x = gp;
        p = parent[x];
    }
    return x;
}

__device__ __forceinline__ void unite(int* parent, int a, int b) {
    while (true) {
        a = find_root(parent, a);
        b = find_root(parent, b);
        if (a == b) return;
        if (a < b) {
            int old = atomicCAS(&parent[b], b, a);
            if (old == b) return;
            b = old;   // coherent value from CAS -> guaranteed progress
        } else {
            int old = atomicCAS(&parent[a], a, b);
            if (old == a) return;
            a = old;
        }
    }
}

// ---------------- kernels ----------------

// 4 px/thread, int4-vectorized
__global__ __launch_bounds__(256) void init_kernel(int* __restrict__ parent,
                                                   int* __restrict__ counts,
                                                   float* __restrict__ acc,
                                                   int* __restrict__ done,
                                                   int n) {
    int idx = blockIdx.x * blockDim.x + threadIdx.x;
    int i4 = idx * 4;
    if (i4 < n) {
        *reinterpret_cast<int4*>(parent + i4) = make_int4(i4, i4 + 1, i4 + 2, i4 + 3);
        *reinterpret_cast<int4*>(counts + i4) = make_int4(0, 0, 0, 0);
    }
    if (idx == 0) { *acc = 0.0f; *done = 0; }
}

// 4 px/thread (same row; W=512 divisible by 4), int4 loads
__global__ __launch_bounds__(256) void merge_kernel(const int* __restrict__ tgt,
                                                    int* __restrict__ parent,
                                                    int n) {
    int i4 = (blockIdx.x * blockDim.x + threadIdx.x) * 4;
    if (i4 >= n) return;
    int4 tv = *reinterpret_cast<const int4*>(tgt + i4);
    int tj[4] = {tv.x, tv.y, tv.z, tv.w};

    // horizontal edges inside the quad
#pragma unroll
    for (int j = 0; j < 3; ++j)
        if (tj[j] > 0 && tj[j + 1] == tj[j]) unite(parent, i4 + j, i4 + j + 1);

    // horizontal edge to next quad (unless at row end)
    int w3 = (i4 + 3) & (IMG_W - 1);
    if (tj[3] > 0 && w3 + 1 < IMG_W) {
        if (tgt[i4 + 4] == tj[3]) unite(parent, i4 + 3, i4 + 4);
    }

    // vertical edges to the row below (same image: h+1 < 512)
    int h = (i4 >> 9) & (IMG_H - 1);
    if (h + 1 < IMG_H) {
        int4 dv = *reinterpret_cast<const int4*>(tgt + i4 + IMG_W);
        int dj[4] = {dv.x, dv.y, dv.z, dv.w};
#pragma unroll
        for (int j = 0; j < 4; ++j)
            if (tj[j] > 0 && dj[j] == tj[j]) unite(parent, i4 + j, i4 + j + IMG_W);
    }
}

// 4 px/thread, int4 target load
__global__ __launch_bounds__(256) void count_kernel(const int* __restrict__ tgt,
                                                    int* __restrict__ parent,
                                                    int* __restrict__ counts,
                                                    int n) {
    int i4 = (blockIdx.x * blockDim.x + threadIdx.x) * 4;
    if (i4 >= n) return;
    int4 tv = *reinterpret_cast<const int4*>(tgt + i4);
    int tj[4] = {tv.x, tv.y, tv.z, tv.w};
#pragma unroll
    for (int j = 0; j < 4; ++j) {
        if (tj[j] > 0) {
            int r = find_root(parent, i4 + j);
            parent[i4 + j] = r;          // full compression: CE reads root directly
            atomicAdd(&counts[r], 1);
        }
    }
}

// 2 px/thread -> 2048 blocks -> 32 waves/CU grid max (TLP for latency hiding)
__global__ __launch_bounds__(256) void ce_weight_kernel(const float* __restrict__ logits,
                                                        const int* __restrict__ tgt,
                                                        const int* __restrict__ parent,
                                                        const int* __restrict__ counts,
                                                        float* __restrict__ acc,
                                                        int* __restrict__ done,
                                                        float* __restrict__ out,
                                                        float inv_n,
                                                        int n_pix,
                                                        int nblocks) {
    int gid  = blockIdx.x * blockDim.x + threadIdx.x;
    int base = gid * 2;
    float local = 0.0f;

    if (base < n_pix) {
        int b   = base >> 18;            // / HWC
        int rem = base & (HWC - 1);
        const float* lp = logits + (size_t)b * NCLS * HWC + rem;

        // all 21 classes x 2 pixels in registers (static indexing)
        float xs[NCLS][2];
#pragma unroll
        for (int c = 0; c < NCLS; ++c) {
            float2 v = *reinterpret_cast<const float2*>(lp + (size_t)c * HWC);
            xs[c][0] = v.x; xs[c][1] = v.y;
        }

        float m[2] = {xs[0][0], xs[0][1]};
#pragma unroll
        for (int c = 1; c < NCLS; ++c) {
            m[0] = fmaxf(m[0], xs[c][0]);
            m[1] = fmaxf(m[1], xs[c][1]);
        }

        float s[2] = {0.f, 0.f};
#pragma unroll
        for (int c = 0; c < NCLS; ++c) {
            s[0] += __expf(xs[c][0] - m[0]);
            s[1] += __expf(xs[c][1] - m[1]);
        }

        int2 t2 = *reinterpret_cast<const int2*>(tgt + base);
        int tj[2] = {t2.x, t2.y};

        float xt[2] = {xs[0][0], xs[0][1]};
#pragma unroll
        for (int c = 1; c < NCLS; ++c) {
            if (tj[0] == c) xt[0] = xs[c][0];
            if (tj[1] == c) xt[1] = xs[c][1];
        }

#pragma unroll
        for (int j = 0; j < 2; ++j) {
            float ce = m[j] + __logf(s[j]) - xt[j];
            float wgt = 1.0f;
            if (tj[j] > 0) {
                int r = parent[base + j];        // fully compressed root
                float size = (float)counts[r];
                if (size < 500.0f)
                    wgt = 3.0f * __logf(size + 1.0f) * INV_LOG_MAXR;
            }
            local += ce * wgt;
        }
    }

    // block reduction: wave64 shuffle, then 4 partials through LDS
#pragma unroll
    for (int off = 32; off > 0; off >>= 1)
        local += __shfl_down(local, off, 64);

    __shared__ float red[4];
    int lane = threadIdx.x & 63;
    int wid  = threadIdx.x >> 6;
    if (lane == 0) red[wid] = local;
    __syncthreads();

    if (threadIdx.x == 0) {
        atomicAdd(acc, red[0] + red[1] + red[2] + red[3]);
        __threadfence();
        int t = atomicAdd(done, 1);
        if (t == nblocks - 1) {
            float a = *(volatile float*)acc;
            out[0] = a * inv_n;
        }
    }
}

// ---------------- launch ----------------

extern "C" void kernel_launch(void* const* d_in, const int* in_sizes, int n_in,
                              void* d_out, int out_size, void* d_ws, size_t ws_size,
                              hipStream_t stream) {
    const float* logits = (const float*)d_in[0];
    const int*   tgt    = (const int*)d_in[1];
    float*       out    = (float*)d_out;

    int n_pix = in_sizes[1];               // B*H*W = 4*512*512 = 1048576

    int*   parent = (int*)d_ws;
    int*   counts = parent + n_pix;
    float* acc    = (float*)(counts + n_pix);
    int*   done   = (int*)(acc + 1);

    int blocks4  = (n_pix / 4 + 255) / 256;   // 1024
    int blocksCE = (n_pix / 2 + 255) / 256;   // 2048

    hipLaunchKernelGGL(init_kernel,  dim3(blocks4), dim3(256), 0, stream, parent, counts, acc, done, n_pix);
    hipLaunchKernelGGL(merge_kernel, dim3(blocks4), dim3(256), 0, stream, tgt, parent, n_pix);
    hipLaunchKernelGGL(count_kernel, dim3(blocks4), dim3(256), 0, stream, tgt, parent, counts, n_pix);
    hipLaunchKernelGGL(ce_weight_kernel, dim3(blocksCE), dim3(256), 0, stream,
                       logits, tgt, parent, counts, acc, done, out,
                       1.0f / (float)n_pix, n_pix, blocksCE);
}

// Round 10
// 203.253 us; speedup vs baseline: 1.1772x; 1.1772x over previous
//
#include <hip/hip_runtime.h>

#define IMG_H 512
#define IMG_W 512
#define NCLS  21
#define HWC   (IMG_H * IMG_W)   // 262144 = 2^18

// 1/ln(501)
#define INV_LOG_MAXR 0.16085936f

// ---------------- union-find ----------------
// Lock-free union-find, union-by-min + path halving (ECL-CC style).
// Plain loads are safe: any published parent value is a true ancestor
// (parents only decrease), CAS return values drive progress in unite(),
// and kernel boundaries make all CAS results visible to plain loads.

__device__ __forceinline__ int find_root(int* parent, int x) {
    int p = parent[x];
    while (p != x) {
        int gp = parent[p];
        if (gp != p) parent[x] = gp;   // path halving: gp is an ancestor
        x = gp;
        p = parent[x];
    }
    return x;
}

__device__ __forceinline__ void unite(int* parent, int a, int b) {
    while (true) {
        a = find_root(parent, a);
        b = find_root(parent, b);
        if (a == b) return;
        if (a < b) {
            int old = atomicCAS(&parent[b], b, a);
            if (old == b) return;
            b = old;   // coherent value from CAS -> guaranteed progress
        } else {
            int old = atomicCAS(&parent[a], a, b);
            if (old == a) return;
            a = old;
        }
    }
}

// ---------------- kernels ----------------

// 4 px/thread, int4-vectorized
__global__ __launch_bounds__(256) void init_kernel(int* __restrict__ parent,
                                                   int* __restrict__ counts,
                                                   float* __restrict__ acc,
                                                   int* __restrict__ done,
                                                   int n) {
    int idx = blockIdx.x * blockDim.x + threadIdx.x;
    int i4 = idx * 4;
    if (i4 < n) {
        *reinterpret_cast<int4*>(parent + i4) = make_int4(i4, i4 + 1, i4 + 2, i4 + 3);
        *reinterpret_cast<int4*>(counts + i4) = make_int4(0, 0, 0, 0);
    }
    if (idx == 0) { *acc = 0.0f; *done = 0; }
}

// 4 px/thread (same row; W=512 divisible by 4), int4 loads
__global__ __launch_bounds__(256) void merge_kernel(const int* __restrict__ tgt,
                                                    int* __restrict__ parent,
                                                    int n) {
    int i4 = (blockIdx.x * blockDim.x + threadIdx.x) * 4;
    if (i4 >= n) return;
    int4 tv = *reinterpret_cast<const int4*>(tgt + i4);
    int tj[4] = {tv.x, tv.y, tv.z, tv.w};

    // horizontal edges inside the quad
#pragma unroll
    for (int j = 0; j < 3; ++j)
        if (tj[j] > 0 && tj[j + 1] == tj[j]) unite(parent, i4 + j, i4 + j + 1);

    // horizontal edge to next quad (unless at row end)
    int w3 = (i4 + 3) & (IMG_W - 1);
    if (tj[3] > 0 && w3 + 1 < IMG_W) {
        if (tgt[i4 + 4] == tj[3]) unite(parent, i4 + 3, i4 + 4);
    }

    // vertical edges to the row below (same image: h+1 < 512)
    int h = (i4 >> 9) & (IMG_H - 1);
    if (h + 1 < IMG_H) {
        int4 dv = *reinterpret_cast<const int4*>(tgt + i4 + IMG_W);
        int dj[4] = {dv.x, dv.y, dv.z, dv.w};
#pragma unroll
        for (int j = 0; j < 4; ++j)
            if (tj[j] > 0 && dj[j] == tj[j]) unite(parent, i4 + j, i4 + j + IMG_W);
    }
}

// 4 px/thread, int4 target load
__global__ __launch_bounds__(256) void count_kernel(const int* __restrict__ tgt,
                                                    int* __restrict__ parent,
                                                    int* __restrict__ counts,
                                                    int n) {
    int i4 = (blockIdx.x * blockDim.x + threadIdx.x) * 4;
    if (i4 >= n) return;
    int4 tv = *reinterpret_cast<const int4*>(tgt + i4);
    int tj[4] = {tv.x, tv.y, tv.z, tv.w};
#pragma unroll
    for (int j = 0; j < 4; ++j) {
        if (tj[j] > 0) {
            int r = find_root(parent, i4 + j);
            parent[i4 + j] = r;          // full compression: CE reads root directly
            atomicAdd(&counts[r], 1);
        }
    }
}

// 4 px/thread, float4 loads. ALL loads issued before ANY consumption:
// sched_barrier(0) pins the 21 class-loads + tgt + parent + counts gathers
// ahead of the compute, forcing ~25 loads in flight per wave (MLP) instead
// of the compiler's register-minimized 2-4. launch_bounds(256,2) gives the
// allocator VGPR headroom (~110 needed) so it doesn't re-sink the loads.
__global__ __launch_bounds__(256, 2) void ce_weight_kernel(
        const float* __restrict__ logits,
        const int*   __restrict__ tgt,
        const int*   __restrict__ parent,
        const int*   __restrict__ counts,
        float* __restrict__ acc,
        int*   __restrict__ done,
        float* __restrict__ out,
        float inv_n,
        int n_pix,
        int nblocks) {
    int gid  = blockIdx.x * blockDim.x + threadIdx.x;
    int base = gid * 4;
    float local = 0.0f;

    if (base < n_pix) {
        int b   = base >> 18;            // / HWC
        int rem = base & (HWC - 1);
        const float* lp = logits + (size_t)b * NCLS * HWC + rem;

        // ---- issue phase: 21 float4 + tgt int4 + parent int4 + 4 count gathers ----
        float4 v[NCLS];
#pragma unroll
        for (int c = 0; c < NCLS; ++c)
            v[c] = *reinterpret_cast<const float4*>(lp + (size_t)c * HWC);

        int4 t4 = *reinterpret_cast<const int4*>(tgt + base);
        int4 p4 = *reinterpret_cast<const int4*>(parent + base);
        // unconditional gather is safe: a background pixel's parent is itself
        // and counts[self]==0 (roots of fg components are always fg pixels).
        int cnt[4];
        cnt[0] = counts[p4.x];
        cnt[1] = counts[p4.y];
        cnt[2] = counts[p4.z];
        cnt[3] = counts[p4.w];

        __builtin_amdgcn_sched_barrier(0);   // nothing moves across: loads stay hoisted

        // ---- compute phase ----
        float xs[NCLS][4];
#pragma unroll
        for (int c = 0; c < NCLS; ++c) {
            xs[c][0] = v[c].x; xs[c][1] = v[c].y; xs[c][2] = v[c].z; xs[c][3] = v[c].w;
        }

        float m[4];
#pragma unroll
        for (int j = 0; j < 4; ++j) m[j] = xs[0][j];
#pragma unroll
        for (int c = 1; c < NCLS; ++c)
#pragma unroll
            for (int j = 0; j < 4; ++j) m[j] = fmaxf(m[j], xs[c][j]);

        float s[4] = {0.f, 0.f, 0.f, 0.f};
#pragma unroll
        for (int c = 0; c < NCLS; ++c)
#pragma unroll
            for (int j = 0; j < 4; ++j) s[j] += __expf(xs[c][j] - m[j]);

        int tj[4] = {t4.x, t4.y, t4.z, t4.w};

        float xt[4];
#pragma unroll
        for (int j = 0; j < 4; ++j) xt[j] = xs[0][j];
#pragma unroll
        for (int c = 1; c < NCLS; ++c)
#pragma unroll
            for (int j = 0; j < 4; ++j)
                if (tj[j] == c) xt[j] = xs[c][j];

#pragma unroll
        for (int j = 0; j < 4; ++j) {
            float ce  = m[j] + __logf(s[j]) - xt[j];
            float size = (float)cnt[j];
            float wgt = (tj[j] > 0 && size < 500.0f)
                        ? 3.0f * __logf(size + 1.0f) * INV_LOG_MAXR
                        : 1.0f;
            local += ce * wgt;
        }
    }

    // block reduction: wave64 shuffle, then 4 partials through LDS
#pragma unroll
    for (int off = 32; off > 0; off >>= 1)
        local += __shfl_down(local, off, 64);

    __shared__ float red[4];
    int lane = threadIdx.x & 63;
    int wid  = threadIdx.x >> 6;
    if (lane == 0) red[wid] = local;
    __syncthreads();

    if (threadIdx.x == 0) {
        atomicAdd(acc, red[0] + red[1] + red[2] + red[3]);
        __threadfence();
        int t = atomicAdd(done, 1);
        if (t == nblocks - 1) {
            float a = *(volatile float*)acc;
            out[0] = a * inv_n;
        }
    }
}

// ---------------- launch ----------------

extern "C" void kernel_launch(void* const* d_in, const int* in_sizes, int n_in,
                              void* d_out, int out_size, void* d_ws, size_t ws_size,
                              hipStream_t stream) {
    const float* logits = (const float*)d_in[0];
    const int*   tgt    = (const int*)d_in[1];
    float*       out    = (float*)d_out;

    int n_pix = in_sizes[1];               // B*H*W = 4*512*512 = 1048576

    int*   parent = (int*)d_ws;
    int*   counts = parent + n_pix;
    float* acc    = (float*)(counts + n_pix);
    int*   done   = (int*)(acc + 1);

    int blocks4 = (n_pix / 4 + 255) / 256;   // 1024

    hipLaunchKernelGGL(init_kernel,  dim3(blocks4), dim3(256), 0, stream, parent, counts, acc, done, n_pix);
    hipLaunchKernelGGL(merge_kernel, dim3(blocks4), dim3(256), 0, stream, tgt, parent, n_pix);
    hipLaunchKernelGGL(count_kernel, dim3(blocks4), dim3(256), 0, stream, tgt, parent, counts, n_pix);
    hipLaunchKernelGGL(ce_weight_kernel, dim3(blocks4), dim3(256), 0, stream,
                       logits, tgt, parent, counts, acc, done, out,
                       1.0f / (float)n_pix, n_pix, blocks4);
}